// Round 1
// 647.222 us; speedup vs baseline: 1.1133x; 1.1133x over previous
//
#include <hip/hip_runtime.h>

// ---------------------------------------------------------------------------
// DecoderLayer (B=2, S=T=2048, D=1024, H=16, DK=64, DF=4096).
// fp32 interface; internal bf16 MFMA. ws = 72 MB:
//   P0..P4 : 5 x 8 MB activation slots
//   Wb     : 32 MB bf16 weights (converted once per launch by conv_all)
// d_out doubles as 16 MB bf16 scratch (F2) until the final LN.
// GEMMs: m97-style pure-bf16 K-loop with global_load_lds(16B) staging.
// flash_attn v2: K via GLL, swizzled P-tile (conflict-free b64 writes),
//   cvt_pk bf16 packing, defer-max rescale, setprio around MFMA,
//   2 barriers/tile (lgkmcnt-only for the wave-private P round trip).
// ---------------------------------------------------------------------------

typedef __bf16 bf16_t;
typedef bf16_t  bf16x8 __attribute__((ext_vector_type(8)));
typedef float   f32x4  __attribute__((ext_vector_type(4)));
typedef unsigned short ushort_t;
typedef ushort_t u16x8 __attribute__((ext_vector_type(8)));
typedef ushort_t u16x4 __attribute__((ext_vector_type(4)));

__device__ __forceinline__ float b2f(ushort_t u) {
    union { unsigned u; float f; } x; x.u = ((unsigned)u) << 16; return x.f;
}
__device__ __forceinline__ ushort_t f2b(float f) {     // RNE
    union { float f; unsigned u; } x; x.f = f;
    unsigned r = x.u + 0x7fffu + ((x.u >> 16) & 1u);
    return (ushort_t)(r >> 16);
}
__device__ __forceinline__ unsigned pk2(float lo, float hi) {
    union { float f; unsigned u; } a, b; a.f = lo; b.f = hi;
    return (b.u & 0xffff0000u) | (a.u >> 16);
}

// global -> LDS direct, 16B per lane (LDS dest = wave-uniform base + lane*16)
#define GLL(gp, lp)                                                            \
    __builtin_amdgcn_global_load_lds(                                          \
        (const __attribute__((address_space(1))) void*)(gp),                   \
        (__attribute__((address_space(3))) void*)(lp), 16, 0, 0)

// ---------------------------------------------------------------------------
// conv_all: fp32 -> bf16 (truncation). 12288 blocks x 256 thr x 8 elems.
// ---------------------------------------------------------------------------
__global__ __launch_bounds__(256) void conv_all(
    const float* __restrict__ x,   const float* __restrict__ enc,
    const float* __restrict__ w0, const float* __restrict__ w1,
    const float* __restrict__ w2, const float* __restrict__ w3,
    const float* __restrict__ w4, const float* __restrict__ w5,
    const float* __restrict__ w6, const float* __restrict__ w7,
    const float* __restrict__ wf1, const float* __restrict__ wf2,
    ushort_t* __restrict__ Xb, ushort_t* __restrict__ Eb,
    ushort_t* __restrict__ Wb)
{
    const int b = blockIdx.x;
    const float* src;
    ushort_t* dst;
    size_t blk;
    if (b < 2048)      { src = x;   dst = Xb; blk = b; }
    else if (b < 4096) { src = enc; dst = Eb; blk = b - 2048; }
    else if (b < 8192) {
        const int i = (b - 4096) >> 9;
        src = (i < 4) ? (i < 2 ? (i == 0 ? w0 : w1) : (i == 2 ? w2 : w3))
                      : (i < 6 ? (i == 4 ? w4 : w5) : (i == 6 ? w6 : w7));
        dst = Wb + (size_t)i * 1048576;
        blk = (b - 4096) & 511;
    }
    else if (b < 10240) { src = wf1; dst = Wb + (size_t)8  * 1048576; blk = b - 8192; }
    else                { src = wf2; dst = Wb + (size_t)12 * 1048576; blk = b - 10240; }

    const size_t e = blk * 2048 + (size_t)threadIdx.x * 8;
    const float4 a = *(const float4*)(src + e);
    const float4 c = *(const float4*)(src + e + 4);
    uint4 r;
    r.x = pk2(a.x, a.y); r.y = pk2(a.z, a.w);
    r.z = pk2(c.x, c.y); r.w = pk2(c.z, c.w);
    *(uint4*)(dst + e) = r;
}

// ---------------------------------------------------------------------------
// GEMM: A[M,K] @ W[N,K]^T + bias (all bf16, GLL staging). TM x 128, BK=32.
// ---------------------------------------------------------------------------
template <int EPI, int TM, bool RF32, bool FUSED, bool SPLITA, bool SPLITC>
__global__ __launch_bounds__(256) void gemm_bt(
    const ushort_t* __restrict__ A, const ushort_t* __restrict__ A2,
    const ushort_t* __restrict__ W,
    const float* __restrict__ b1, const float* __restrict__ b2,
    const float* __restrict__ b3,
    const void* __restrict__ Rv,
    ushort_t* __restrict__ C, ushort_t* __restrict__ C2,
    int M, int N, int K)
{
    constexpr int IM = TM / 32;                 // acc rows per wave
    __shared__ __align__(16) ushort_t At[TM * 32];
    __shared__ __align__(16) ushort_t Bt[128 * 32];

    const int tid  = threadIdx.x;
    const int lane = tid & 63, w = tid >> 6;
    const int g = lane >> 4, qi = lane & 15;
    const int bm = blockIdx.y * TM, bn = blockIdx.x * 128;
    const int wm = (w >> 1) * (TM / 2), wn = (w & 1) * 64;

    const ushort_t* Ap = SPLITA ? ((bm < 2048) ? A : A2) : A;
    const int       am = SPLITA ? (bm & 2047) : bm;

    const int srow = lane >> 2;          // row within a 16-row segment
    const int scol = (lane & 3) * 8;     // bf16 col within 32

    f32x4 acc[IM][4] = {};

    const int niter = K >> 5;
    for (int kt = 0; kt < niter; ++kt) {
        const int k0 = kt << 5;
        __syncthreads();
        // A tile: TM/16 segments of 16 rows; one GLL covers one segment
        if (TM == 128) {
#pragma unroll
            for (int c = 0; c < 2; ++c) {
                const int s = c * 4 + w;
                GLL(Ap + (size_t)(am + s * 16 + srow) * K + k0 + scol, At + s * 512);
            }
        } else {  // TM == 64
            GLL(Ap + (size_t)(am + w * 16 + srow) * K + k0 + scol, At + w * 512);
        }
        // W tile: 128 rows = 8 segments
#pragma unroll
        for (int c = 0; c < 2; ++c) {
            const int s = c * 4 + w;
            GLL(W + (size_t)(bn + s * 16 + srow) * K + k0 + scol, Bt + s * 512);
        }
        __syncthreads();

        bf16x8 af[IM], bfr[4];
#pragma unroll
        for (int i = 0; i < IM; ++i)
            af[i] = *(const bf16x8*)(At + (wm + i * 16 + qi) * 32 + g * 8);
#pragma unroll
        for (int j = 0; j < 4; ++j)
            bfr[j] = *(const bf16x8*)(Bt + (wn + j * 16 + qi) * 32 + g * 8);
#pragma unroll
        for (int i = 0; i < IM; ++i)
#pragma unroll
            for (int j = 0; j < 4; ++j)
                acc[i][j] = __builtin_amdgcn_mfma_f32_16x16x32_bf16(
                    af[i], bfr[j], acc[i][j], 0, 0, 0);
    }

    // C-layout: col(n) = lane&15, row(m) = (lane>>4)*4 + r
    const float* bp = FUSED ? (bn < 1024 ? b1 : (bn < 2048 ? b2 : b3)) : b1;
#pragma unroll
    for (int j = 0; j < 4; ++j) {
        const int n = bn + wn + j * 16 + qi;
        const int nl = n & 1023;
        const float bv = bp[nl];
#pragma unroll
        for (int i = 0; i < IM; ++i) {
#pragma unroll
            for (int r = 0; r < 4; ++r) {
                const int m = bm + wm + i * 16 + g * 4 + r;
                float v = acc[i][j][r] + bv;
                if (EPI == 2) {
                    v += RF32 ? ((const float*)Rv)[(size_t)m * N + n]
                              : b2f(((const ushort_t*)Rv)[(size_t)m * N + n]);
                }
                if (EPI == 3) v = v > 0.f ? v : 0.f;
                if (EPI == 1) {
                    const int which = FUSED ? (bn >> 10) : 0;
                    const int bb = m >> 11, s = m & 2047;    // S = 2048
                    const int h = nl >> 6, dk = nl & 63;
                    const size_t dst = (size_t)which * 4194304 +
                        (((size_t)((bb << 4) + h)) * 2048 + s) * 64 + dk;
                    C[dst] = f2b(v);
                } else {
                    ushort_t* Cp = SPLITC ? (m < 2048 ? C : C2) : C;
                    const int mr = SPLITC ? (m & 2047) : m;
                    Cp[(size_t)mr * N + n] = f2b(v);
                }
            }
        }
    }
}

// ---------------------------------------------------------------------------
// Flash attention v2. Q,K,V: bf16 [B*H, S, 64]; O: bf16 [B*S, 1024].
// 64 q-rows/block (4 waves x 16), 32-key tiles.
//   - K tile staged via GLL with pre-permuted source (layout identical to v1)
//   - P tile: XOR-swizzled (col16 ^= (qi>>1)&3), packed b64 writes via
//     v_cvt_pk_bf16_f32; wave-private -> lgkmcnt(0) instead of barrier
//   - defer-max: rescale O/l only when row-max grows by > 8 (scaled)
// ---------------------------------------------------------------------------
template <bool CAUSAL>
__global__ __launch_bounds__(256) void flash_attn(
    const ushort_t* __restrict__ Q, const ushort_t* __restrict__ K,
    const ushort_t* __restrict__ V, ushort_t* __restrict__ O, int S)
{
    __shared__ __align__(16) ushort_t Kt[2 * 32 * 32];
    __shared__ __align__(16) ushort_t Vt[64 * 40];
    __shared__ __align__(16) ushort_t Pl[4 * 16 * 32];

    const int tid = threadIdx.x, lane = tid & 63, w = tid >> 6;
    const int g = lane >> 4, qi = lane & 15;
    const int q2 = (qi >> 1) & 3;            // P-tile swizzle key
    const int bh = blockIdx.y;
    const size_t base = (size_t)bh * S * 64;
    const int q0 = blockIdx.x * 64;
    const int qw = q0 + w * 16;

    // K GLL source decomposition: wave w fills Kt elements [w*512, w*512+512).
    // Kt element e: khalf = e>>10, k = (e>>5)&31, d = khalf*32 + (e&31).
    const int krow2 = ((w & 1) << 4) + (lane >> 2);
    const int kcol2 = ((w >> 1) << 5) + ((lane & 3) << 3);

    bf16x8 qf0 = *(const bf16x8*)(Q + base + (size_t)(qw + qi) * 64 + g * 8);
    bf16x8 qf1 = *(const bf16x8*)(Q + base + (size_t)(qw + qi) * 64 + 32 + g * 8);

    f32x4 oacc[4] = {};
    float m_i = -1e30f, l_i = 0.f;

    const int ntiles = CAUSAL ? ((q0 >> 5) + 2) : (S >> 5);
    for (int t = 0; t < ntiles; ++t) {
        const int k0 = t << 5;
        // V^T staging loads (register; coalesced 128B per row-instr)
        u16x8 pk;
#pragma unroll
        for (int j = 0; j < 8; ++j)
            pk[j] = V[base + (size_t)(k0 + w * 8 + j) * 64 + lane];
        __syncthreads();                 // prev-tile LDS reads done
        GLL(K + base + (size_t)(k0 + krow2) * 64 + kcol2, Kt + w * 512);
        *(u16x8*)(Vt + lane * 40 + w * 8) = pk;
        __syncthreads();                 // drains vmcnt (GLL) + lgkm

        f32x4 st[2] = {};
        __builtin_amdgcn_s_setprio(1);
#pragma unroll
        for (int tt = 0; tt < 2; ++tt) {
            bf16x8 kf0 = *(const bf16x8*)(Kt + (tt * 16 + qi) * 32 + g * 8);
            bf16x8 kf1 = *(const bf16x8*)(Kt + 1024 + (tt * 16 + qi) * 32 + g * 8);
            st[tt] = __builtin_amdgcn_mfma_f32_16x16x32_bf16(kf0, qf0, st[tt], 0, 0, 0);
            st[tt] = __builtin_amdgcn_mfma_f32_16x16x32_bf16(kf1, qf1, st[tt], 0, 0, 0);
        }
        __builtin_amdgcn_s_setprio(0);

        if (CAUSAL && (k0 + 31 > qw)) {
#pragma unroll
            for (int tt = 0; tt < 2; ++tt)
#pragma unroll
                for (int r = 0; r < 4; ++r)
                    if (k0 + tt * 16 + g * 4 + r > qw + qi) st[tt][r] = -1e30f;
        }

        float mx = st[0][0];
#pragma unroll
        for (int r = 1; r < 4; ++r) mx = fmaxf(mx, st[0][r]);
#pragma unroll
        for (int r = 0; r < 4; ++r) mx = fmaxf(mx, st[1][r]);
        mx = fmaxf(mx, __shfl_xor(mx, 16));
        mx = fmaxf(mx, __shfl_xor(mx, 32));

        // defer-max: only rescale when some row's max grew by >8 (scaled).
        // P is then bounded by e^8 ~ 2981 (fine in bf16 / fp32 accum).
        if (!__all(mx - m_i <= 64.f)) {
            const float m_new = fmaxf(m_i, mx);
            const float alpha = __expf((m_i - m_new) * 0.125f);
            float av[4];
#pragma unroll
            for (int r = 0; r < 4; ++r) av[r] = __shfl(alpha, g * 4 + r, 16);
#pragma unroll
            for (int dt = 0; dt < 4; ++dt)
#pragma unroll
                for (int r = 0; r < 4; ++r) oacc[dt][r] *= av[r];
            l_i *= alpha;
            m_i = m_new;
        }

        float p[2][4];
        float psum = 0.f;
#pragma unroll
        for (int tt = 0; tt < 2; ++tt)
#pragma unroll
            for (int r = 0; r < 4; ++r) {
                p[tt][r] = __expf((st[tt][r] - m_i) * 0.125f);
                psum += p[tt][r];
            }
        psum += __shfl_xor(psum, 16);
        psum += __shfl_xor(psum, 32);
        l_i += psum;

        // P round trip (wave-private region, swizzled, conflict-free b64)
        ushort_t* pb = Pl + w * 512;
#pragma unroll
        for (int tt = 0; tt < 2; ++tt) {
            unsigned lo, hi;
            asm("v_cvt_pk_bf16_f32 %0, %1, %2" : "=v"(lo) : "v"(p[tt][0]), "v"(p[tt][1]));
            asm("v_cvt_pk_bf16_f32 %0, %1, %2" : "=v"(hi) : "v"(p[tt][2]), "v"(p[tt][3]));
            const int swc = (tt * 2 + (g >> 1)) ^ q2;
            uint2 pw; pw.x = lo; pw.y = hi;
            *(uint2*)(pb + qi * 32 + swc * 8 + (g & 1) * 4) = pw;
        }
        asm volatile("s_waitcnt lgkmcnt(0)" ::: "memory");
        __builtin_amdgcn_sched_barrier(0);
        bf16x8 pf = *(const bf16x8*)(pb + qi * 32 + ((g ^ q2) << 3));

        __builtin_amdgcn_s_setprio(1);
#pragma unroll
        for (int dt = 0; dt < 4; ++dt) {
            bf16x8 vf = *(const bf16x8*)(Vt + (dt * 16 + qi) * 40 + g * 8);
            oacc[dt] = __builtin_amdgcn_mfma_f32_16x16x32_bf16(pf, vf, oacc[dt], 0, 0, 0);
        }
        __builtin_amdgcn_s_setprio(0);
    }

    float lv[4];
#pragma unroll
    for (int r = 0; r < 4; ++r) lv[r] = 1.f / __shfl(l_i, g * 4 + r, 16);

    const int b = bh >> 4, h = bh & 15;
#pragma unroll
    for (int dt = 0; dt < 4; ++dt)
#pragma unroll
        for (int r = 0; r < 4; ++r) {
            const int row = b * S + qw + g * 4 + r;
            const int col = (h << 6) + dt * 16 + qi;
            O[(size_t)row * 1024 + col] = f2b(oacc[dt][r] * lv[r]);
        }
}

// ---------------------------------------------------------------------------
// LayerNorm D=1024. X bf16 ws; gamma/beta fp32; OUT fp32 (final) or bf16.
// ---------------------------------------------------------------------------
template <bool OUTF32>
__global__ __launch_bounds__(256) void ln_kernel(
    const ushort_t* __restrict__ X, const float* __restrict__ gam,
    const float* __restrict__ bet, void* __restrict__ Yv)
{
    const int row = blockIdx.x, tid = threadIdx.x;
    const int lane = tid & 63, w = tid >> 6;
    const size_t off = (size_t)row * 1024 + tid * 4;

    u16x4 xv = *(const u16x4*)(X + off);
    float f[4];
#pragma unroll
    for (int i = 0; i < 4; ++i) f[i] = b2f(xv[i]);

    float s = f[0] + f[1] + f[2] + f[3];
    float sq = f[0] * f[0] + f[1] * f[1] + f[2] * f[2] + f[3] * f[3];
#pragma unroll
    for (int o = 32; o; o >>= 1) {
        s  += __shfl_xor(s, o);
        sq += __shfl_xor(sq, o);
    }
    __shared__ float red[8];
    if (lane == 0) { red[w] = s; red[4 + w] = sq; }
    __syncthreads();
    s  = red[0] + red[1] + red[2] + red[3];
    sq = red[4] + red[5] + red[6] + red[7];

    const float mu = s * (1.f / 1024.f);
    const float var = sq * (1.f / 1024.f) - mu * mu;
    const float rs = rsqrtf(var + 1e-5f);

    const float4 gv = *(const float4*)(gam + tid * 4);
    const float4 bv = *(const float4*)(bet + tid * 4);
    float y0 = (f[0] - mu) * rs * gv.x + bv.x;
    float y1 = (f[1] - mu) * rs * gv.y + bv.y;
    float y2 = (f[2] - mu) * rs * gv.z + bv.z;
    float y3 = (f[3] - mu) * rs * gv.w + bv.w;

    if (OUTF32) {
        float4 yv; yv.x = y0; yv.y = y1; yv.z = y2; yv.w = y3;
        *(float4*)((float*)Yv + off) = yv;
    } else {
        u16x4 yv;
        yv[0] = f2b(y0); yv[1] = f2b(y1); yv[2] = f2b(y2); yv[3] = f2b(y3);
        *(u16x4*)((ushort_t*)Yv + off) = yv;
    }
}

// ---------------------------------------------------------------------------
extern "C" void kernel_launch(void* const* d_in, const int* in_sizes, int n_in,
                              void* d_out, int out_size, void* d_ws, size_t ws_size,
                              hipStream_t stream)
{
    const float* x   = (const float*)d_in[0];
    const float* enc = (const float*)d_in[1];
    const float* Wq1 = (const float*)d_in[4];
    const float* bq1 = (const float*)d_in[5];
    const float* Wk1 = (const float*)d_in[6];
    const float* bk1 = (const float*)d_in[7];
    const float* Wv1 = (const float*)d_in[8];
    const float* bv1 = (const float*)d_in[9];
    const float* Wo1 = (const float*)d_in[10];
    const float* bo1 = (const float*)d_in[11];
    const float* Wq2 = (const float*)d_in[12];
    const float* bq2 = (const float*)d_in[13];
    const float* Wk2 = (const float*)d_in[14];
    const float* bk2 = (const float*)d_in[15];
    const float* Wv2 = (const float*)d_in[16];
    const float* bv2 = (const float*)d_in[17];
    const float* Wo2 = (const float*)d_in[18];
    const float* bo2 = (const float*)d_in[19];
    const float* Wf1 = (const float*)d_in[20];
    const float* bf1 = (const float*)d_in[21];
    const float* Wf2 = (const float*)d_in[22];
    const float* bf2 = (const float*)d_in[23];
    const float* gm1 = (const float*)d_in[24];
    const float* be1 = (const float*)d_in[25];
    const float* gm2 = (const float*)d_in[26];
    const float* be2 = (const float*)d_in[27];
    const float* gm3 = (const float*)d_in[28];
    const float* be3 = (const float*)d_in[29];

    float*    out = (float*)d_out;
    ushort_t* ws  = (ushort_t*)d_ws;
    ushort_t* F2  = (ushort_t*)d_out;   // 16 MB bf16 scratch until final LN

    const size_t E = (size_t)4096 * 1024;
    ushort_t* P0 = ws;
    ushort_t* P1 = ws + 1 * E;
    ushort_t* P2 = ws + 2 * E;
    ushort_t* P3 = ws + 3 * E;
    ushort_t* P4 = ws + 4 * E;
    ushort_t* Wb = ws + 5 * E;          // 16M bf16 weights (32 MB)

    const size_t M1 = 1048576;
    ushort_t* Wb_qkv1 = Wb;              // q1,k1,v1 contiguous
    ushort_t* Wb_o1   = Wb + 3 * M1;
    ushort_t* Wb_q2   = Wb + 4 * M1;
    ushort_t* Wb_kv2  = Wb + 5 * M1;     // k2,v2 contiguous
    ushort_t* Wb_o2   = Wb + 7 * M1;
    ushort_t* Wb_f1   = Wb + 8 * M1;
    ushort_t* Wb_f2   = Wb + 12 * M1;

    const dim3 blk(256);
    const dim3 gA(32, 32);

    // ---- convert x, enc, all weights to bf16 ----
    conv_all<<<12288, blk, 0, stream>>>(x, enc, Wq1, Wk1, Wv1, Wo1, Wq2, Wk2,
                                        Wv2, Wo2, Wf1, Wf2, P3, P4, Wb);

    // ---- self attention ----
    gemm_bt<1, 128, false, true, false, false><<<dim3(24, 32), blk, 0, stream>>>(
        P3, nullptr, Wb_qkv1, bq1, bk1, bv1, nullptr, P0, nullptr, 4096, 3072, 1024);
    flash_attn<true><<<gA, blk, 0, stream>>>(P0, P1, P2, P3, 2048);
    gemm_bt<2, 64, true, false, false, false><<<dim3(8, 64), blk, 0, stream>>>(
        P3, nullptr, Wb_o1, bo1, bo1, bo1, x, P0, nullptr, 4096, 1024, 1024);
    ln_kernel<false><<<4096, blk, 0, stream>>>(P0, gm1, be1, P1);   // X1 = P1

    // ---- cross attention ----
    gemm_bt<1, 64, false, false, false, false><<<dim3(8, 64), blk, 0, stream>>>(
        P1, nullptr, Wb_q2, bq2, bq2, bq2, nullptr, P0, nullptr, 4096, 1024, 1024);
    gemm_bt<1, 128, false, true, false, false><<<dim3(16, 32), blk, 0, stream>>>(
        P4, nullptr, Wb_kv2, bk2, bv2, bv2, nullptr, P2, nullptr, 4096, 2048, 1024);
    flash_attn<false><<<gA, blk, 0, stream>>>(P0, P2, P3, P4, 2048);
    gemm_bt<2, 64, false, false, false, false><<<dim3(8, 64), blk, 0, stream>>>(
        P4, nullptr, Wb_o2, bo2, bo2, bo2, P1, P0, nullptr, 4096, 1024, 1024);
    ln_kernel<false><<<4096, blk, 0, stream>>>(P0, gm2, be2, P2);   // X2 = P2

    // ---- FFN ----
    gemm_bt<3, 128, false, false, false, true><<<dim3(32, 32), blk, 0, stream>>>(
        P2, nullptr, Wb_f1, bf1, bf1, bf1, nullptr, P0, F2, 4096, 4096, 1024);
    gemm_bt<2, 64, false, false, true, false><<<dim3(8, 64), blk, 0, stream>>>(
        P0, F2, Wb_f2, bf2, bf2, bf2, P2, P3, nullptr, 4096, 1024, 4096);
    ln_kernel<true><<<4096, blk, 0, stream>>>(P3, gm3, be3, out);
}